// Round 8
// baseline (153.763 us; speedup 1.0000x reference)
//
#include <hip/hip_runtime.h>

// Two-kernel MoE. B=4,S=4096,DIM=2048,BITS=32,HEXP=4 (f32).
// out[t,d] = x[t,d] * ( sum_e v[t,e]*aggr_w[e]*emb[idx[t,e],d] + aggr_b )
// (v,idx) = top4(softmax(x[t]@A1_w.T + A1_b)), descending, ties->lower idx.
//
// K1 router: grid 512 x 512 thr (8 waves), block = 32 tokens. NO LDS in the
//   main loop. Wave wid owns dims [256*wid, +256). Lane = (t = lane&15 ->
//   tokens {t, t+16}, h = lane>>4 -> 4 dims of each 16-dim chunk).
//   W: plain global dwordx4 per lane; the 16 token-lanes of each h share ONE
//   64B line -> TA coalesces to a single L1/L2 line fetch. W total 256KB =
//   L2-resident; traffic 512 blocks * 256KB = 128MB of L2 reads (~4us).
//   x: global->VGPR, 1 f4 per token per chunk (h-groups cover the line).
//   Each W line feeds 2 tokens * 4 dims = 8 FMA/lane -> VALU-bound.
//   Epilogue: shfl_xor(16|32) h-combine -> red[8][32][36] -> softmax/top4
//   (1 thread/token, lax.top_k ties->lower) -> gates to d_ws.
// K2 combine: verbatim from the 98.9us round.

#define NTOK 16384
#define DIMV 2048

__global__ __launch_bounds__(512, 4) void router_k(
    const float* __restrict__ x,
    const float* __restrict__ A1w,
    const float* __restrict__ A1b,
    const float* __restrict__ aggw,
    float* __restrict__ gates)
{
    __shared__ float smem[9216];               // red[8][32][36] only (36KB)

    const int tid  = threadIdx.x;
    const int lane = tid & 63;
    const int wid  = tid >> 6;
    const int t    = lane & 15;                // token pair {t, t+16}
    const int h    = lane >> 4;                // dim sub-position (4 dims)
    const int tok0 = blockIdx.x << 5;          // 32 tokens/block
    const int dbase = (wid << 8) + (h << 2);   // wave slice + lane offset

    const float* xrowA = x + (size_t)(tok0 + t)      * DIMV + dbase;
    const float* xrowB = x + (size_t)(tok0 + t + 16) * DIMV + dbase;
    const float* wbase = A1w + dbase;

    float acc0[32], acc1[32];
    #pragma unroll
    for (int k = 0; k < 32; ++k) { acc0[k] = 0.f; acc1[k] = 0.f; }

    float4 xa = *(const float4*)(xrowA);
    float4 xb = *(const float4*)(xrowB);

    for (int c = 0; c < 16; ++c) {
        const int cn = (c < 15) ? (c + 1) : 15;      // last iter: harmless reload
        const float4 xna = *(const float4*)(xrowA + (cn << 4));
        const float4 xnb = *(const float4*)(xrowB + (cn << 4));
        const float* wc = wbase + (c << 4);
        #pragma unroll
        for (int k = 0; k < 32; ++k) {
            const float4 w = *(const float4*)(wc + k * DIMV);
            float a = acc0[k], b = acc1[k];
            a = fmaf(xa.x, w.x, a); a = fmaf(xa.y, w.y, a);
            a = fmaf(xa.z, w.z, a); a = fmaf(xa.w, w.w, a);
            b = fmaf(xb.x, w.x, b); b = fmaf(xb.y, w.y, b);
            b = fmaf(xb.z, w.z, b); b = fmaf(xb.w, w.w, b);
            acc0[k] = a; acc1[k] = b;
        }
        xa = xna; xb = xnb;
    }

    // combine h-groups: xor 16 merges h0/h1 (h2/h3), xor 32 merges the pairs
    #pragma unroll
    for (int k = 0; k < 32; ++k) {
        float a = acc0[k], b = acc1[k];
        a += __shfl_xor(a, 16); a += __shfl_xor(a, 32);
        b += __shfl_xor(b, 16); b += __shfl_xor(b, 32);
        acc0[k] = a; acc1[k] = b;
    }

    float* red = smem;                          // red[8][32][36]
    if (lane < 16) {
        float* r0 = red + wid * 1152 + t * 36;
        float* r1 = red + wid * 1152 + (t + 16) * 36;
        #pragma unroll
        for (int q = 0; q < 8; ++q) {
            *(float4*)&r0[q << 2] = make_float4(acc0[4*q], acc0[4*q+1],
                                                acc0[4*q+2], acc0[4*q+3]);
            *(float4*)&r1[q << 2] = make_float4(acc1[4*q], acc1[4*q+1],
                                                acc1[4*q+2], acc1[4*q+3]);
        }
    }
    __syncthreads();

    // softmax + top4 + gates: one thread per token (32 of 512)
    if (tid < 32) {
        const int tt = tid;
        float l[32];
        #pragma unroll
        for (int q = 0; q < 8; ++q) {
            float4 v = make_float4(0.f, 0.f, 0.f, 0.f);
            #pragma unroll
            for (int w = 0; w < 8; ++w) {
                const float4 p = *(const float4*)&red[w * 1152 + tt * 36 + (q << 2)];
                v.x += p.x; v.y += p.y; v.z += p.z; v.w += p.w;
            }
            l[4*q]   = v.x + A1b[4*q];
            l[4*q+1] = v.y + A1b[4*q+1];
            l[4*q+2] = v.z + A1b[4*q+2];
            l[4*q+3] = v.w + A1b[4*q+3];
        }
        float m = l[0];
        #pragma unroll
        for (int k = 1; k < 32; ++k) m = fmaxf(m, l[k]);
        float s = 0.f;
        #pragma unroll
        for (int k = 0; k < 32; ++k) { l[k] = expf(l[k] - m); s += l[k]; }
        const float inv = 1.0f / s;

        unsigned used = 0u;
        float gv[4]; unsigned iv[4];
        #pragma unroll
        for (int e = 0; e < 4; ++e) {
            float best = -1.f; int bi = 0;
            #pragma unroll
            for (int k = 0; k < 32; ++k) {
                bool ok = !((used >> k) & 1u) && (l[k] > best);
                best = ok ? l[k] : best;
                bi   = ok ? k    : bi;
            }
            used |= (1u << bi);
            gv[e] = best * inv * aggw[e];       // gate * aggr_w[e]
            iv[e] = (unsigned)bi;
        }
        float* gp = gates + (size_t)(tok0 + tt) * 8;
        *(float4*)gp = make_float4(gv[0], gv[1], gv[2], gv[3]);
        *(float4*)(gp + 4) = make_float4(__uint_as_float(iv[0]), __uint_as_float(iv[1]),
                                         __uint_as_float(iv[2]), __uint_as_float(iv[3]));
    }
}

// K2: gather + combine + residual (verbatim from the 98.9us round).
__global__ __launch_bounds__(256) void moe_out_k(
    const float* __restrict__ x,
    const float* __restrict__ emb,
    const float* __restrict__ gates,
    const float* __restrict__ aggb,
    float* __restrict__ out)
{
    const int t   = blockIdx.x;
    const int tid = threadIdx.x;
    const float* gp = gates + (size_t)t * 8;
    const float4 g  = *(const float4*)gp;
    const float4 ibits = *(const float4*)(gp + 4);
    const unsigned i0 = __float_as_uint(ibits.x);
    const unsigned i1 = __float_as_uint(ibits.y);
    const unsigned i2 = __float_as_uint(ibits.z);
    const unsigned i3 = __float_as_uint(ibits.w);
    const float b = aggb[0];
    const size_t base = (size_t)t * DIMV;

    #pragma unroll
    for (int h = 0; h < DIMV; h += 1024) {
        const int d = h + (tid << 2);
        const float4 xv = *(const float4*)&x[base + d];
        const float4 e0 = *(const float4*)&emb[(size_t)i0 * DIMV + d];
        const float4 e1 = *(const float4*)&emb[(size_t)i1 * DIMV + d];
        const float4 e2 = *(const float4*)&emb[(size_t)i2 * DIMV + d];
        const float4 e3 = *(const float4*)&emb[(size_t)i3 * DIMV + d];
        float4 a, o;
        a.x = fmaf(g.x, e0.x, fmaf(g.y, e1.x, fmaf(g.z, e2.x, fmaf(g.w, e3.x, b))));
        a.y = fmaf(g.x, e0.y, fmaf(g.y, e1.y, fmaf(g.z, e2.y, fmaf(g.w, e3.y, b))));
        a.z = fmaf(g.x, e0.z, fmaf(g.y, e1.z, fmaf(g.z, e2.z, fmaf(g.w, e3.z, b))));
        a.w = fmaf(g.x, e0.w, fmaf(g.y, e1.w, fmaf(g.z, e2.w, fmaf(g.w, e3.w, b))));
        o.x = xv.x * a.x; o.y = xv.y * a.y; o.z = xv.z * a.z; o.w = xv.w * a.w;
        *(float4*)&out[base + d] = o;
    }
}

extern "C" void kernel_launch(void* const* d_in, const int* in_sizes, int n_in,
                              void* d_out, int out_size, void* d_ws, size_t ws_size,
                              hipStream_t stream)
{
    (void)in_sizes; (void)n_in; (void)out_size; (void)ws_size;
    const float* x    = (const float*)d_in[0];
    const float* A1w  = (const float*)d_in[1];
    const float* A1b  = (const float*)d_in[2];
    const float* emb  = (const float*)d_in[3];
    const float* aggw = (const float*)d_in[4];
    const float* aggb = (const float*)d_in[5];
    float* out   = (float*)d_out;
    float* gates = (float*)d_ws;               // 16384 * 8 f32 = 512 KB

    router_k<<<NTOK / 32, 512, 0, stream>>>(x, A1w, A1b, aggw, gates);
    moe_out_k<<<NTOK, 256, 0, stream>>>(x, emb, gates, aggb, out);
}